// Round 11
// baseline (204.427 us; speedup 1.0000x reference)
//
#include <hip/hip_runtime.h>
#include <stdint.h>

// Batched tiny MLP [B,13]->16->(30x 16->16 relu)->1, fp32 in/out, f16 MFMA.
// R11: K-dilated 16x16x32 MFMA. The legacy 16x16x16 shape measured ~16.3
// cyc/instr (1/7 rate); the gfx950-native 16x16x32 runs ~4.85 cyc. Our K is
// only 16, so dilate: A'[m][8g+j] = W[m][4g+j] for j<4 else 0 (g=k>>3).
// Then each lane's 4 MFMA D values (rows 4g..4g+3, col=lane&15) are exactly
// its own B-operand positions k=8g..8g+3 for the next layer -- zero cross-
// lane movement preserved, B frag = {pk(d0,d1), pk(d2,d3), 0, 0}.
// Weight LDS image is bit-identical to R8; zeros are appended in registers.

typedef __attribute__((ext_vector_type(8))) _Float16 half8v;
typedef __attribute__((ext_vector_type(2))) _Float16 h2;
typedef __attribute__((ext_vector_type(4))) float float4v;

#define S_IN 13
#define H 16
#define NL 32            // mfma layers: 0 = input, 1..30 = hidden, 31 = output
#define TPB 512
#define WPB 8            // waves per block
#define T 4              // 16-sample tiles per wave per iteration
#define NBLOCKS 768      // 3 blocks/CU * 256 CUs (LDS-limited residency)
#define STRIDE (NBLOCKS * WPB * T)   // tiles per grid sweep = 24576

// LDS dword map:
//   [0, 4096)            A-frags: 2 dwords (4 f16, k-positions j<4) per (L,lane)
//   [4096, 4608)         bias[L][m] fp32 (C-operand order)
//   [4608, 4608+WPB*832) per-wave x staging (4 tiles * 16 samples * 13 dw)
//   +4 zero pad (input-frag gather may overshoot by up to 3 dwords)
#define XS_BASE 4608
#define LDS_DW (XS_BASE + WPB * 832 + 4)

__device__ __forceinline__ unsigned pkh(float a, float b) {
    return __builtin_bit_cast(unsigned, __builtin_amdgcn_cvt_pkrtz(a, b));
}

// build an 8-f16 fragment from two packed dwords + two zero dwords
__device__ __forceinline__ half8v frag8(unsigned lo, unsigned hi) {
    int4 q;
    q.x = (int)lo; q.y = (int)hi; q.z = 0; q.w = 0;
    return __builtin_bit_cast(half8v, q);
}

// cvt then packed-f16 relu: 2 cvt + 2 v_pk_max_f16, zeros in k-slots 4..7
__device__ __forceinline__ half8v relu_frag8(const float4v& d) {
    const h2 z = {(_Float16)0.f, (_Float16)0.f};
    h2 lo = __builtin_bit_cast(h2, pkh(d[0], d[1]));
    h2 hi = __builtin_bit_cast(h2, pkh(d[2], d[3]));
    lo = __builtin_elementwise_max(lo, z);
    hi = __builtin_elementwise_max(hi, z);
    return frag8(__builtin_bit_cast(unsigned, lo), __builtin_bit_cast(unsigned, hi));
}

__global__ __launch_bounds__(TPB, 6)
void mlp_kernel(const float* __restrict__ x,
                const float* __restrict__ W_in, const float* __restrict__ b_in,
                const float* __restrict__ W_h,  const float* __restrict__ b_h,
                const float* __restrict__ W_out,const float* __restrict__ b_out,
                float* __restrict__ out, int tiles)
{
    __shared__ unsigned lds[LDS_DW];
    const int tid = threadIdx.x;

    // ---- swizzle weights into dilated A-fragment image (once per block) ----
    // lane holds A'[m=lane&15][k=8g+j]: j<4 -> W[m][4g+j] (2 packed dwords in
    // LDS), j>=4 -> 0 (appended in registers at use).
    for (int s = tid; s < NL * 64; s += TPB) {
        const int L = s >> 6, ln = s & 63, m = ln & 15, gg = ln >> 4;
        float v[4];
#pragma unroll
        for (int i = 0; i < 4; ++i) {
            const int k = 4 * gg + i;
            if (L == 0)       v[i] = (k < S_IN) ? W_in[m * S_IN + k] : 0.f;
            else if (L <= 30) v[i] = W_h[(L - 1) * H * H + m * H + k];
            else              v[i] = (m == 0) ? W_out[k] : 0.f;
        }
        lds[s * 2]     = pkh(v[0], v[1]);
        lds[s * 2 + 1] = pkh(v[2], v[3]);
    }
    for (int s = tid; s < NL * H; s += TPB) {
        const int L = s >> 4, m = s & 15;
        float bv;
        if (L == 0)       bv = b_in[m];
        else if (L <= 30) bv = b_h[(L - 1) * H + m];
        else              bv = (m == 0) ? b_out[0] : 0.f;
        lds[4096 + s] = __float_as_uint(bv);
    }
    if (tid < 4) lds[XS_BASE + WPB * 832 + tid] = 0;   // zero overshoot pad
    __syncthreads();

    const uint2* lA = (const uint2*)lds;               // [NL*64] packed pairs
    const float4v* lB = (const float4v*)(lds + 4096);  // [NL*4]

    const int lane = tid & 63;
    const int wv   = tid >> 6;
    const int g    = lane >> 4;
    const int col  = lane & 15;
    const int k0   = 4 * g;
    const int col13k = col * 13 + k0;

    unsigned* xs = lds + XS_BASE + wv * 832;           // wave-private staging

    const int wave_id = blockIdx.x * WPB + wv;
    int tb = wave_id * T;
    if (tb >= tiles) return;

    float* op = out + (size_t)tb * 16 + lane;

    // prefetch first iteration's x block (4 tiles = 832 dwords, coalesced)
    const float* xp = x + (size_t)tb * 208;
    float4v r0 = *(const float4v*)(xp + lane * 4);
    float4v r1 = *(const float4v*)(xp + 256 + lane * 4);
    float4v r2 = *(const float4v*)(xp + 512 + lane * 4);
    float    r3 = xp[768 + lane];

    for (; tb < tiles; tb += STRIDE) {
        // stage current x block (wave-private: no barrier needed)
        *(float4v*)(xs + lane * 4)       = r0;
        *(float4v*)(xs + 256 + lane * 4) = r1;
        *(float4v*)(xs + 512 + lane * 4) = r2;
        xs[768 + lane] = __float_as_uint(r3);

        // issue next iteration's global loads (in flight across layer chain)
        const int tbn = tb + STRIDE;
        if (tbn < tiles) {
            xp = x + (size_t)tbn * 208;
            r0 = *(const float4v*)(xp + lane * 4);
            r1 = *(const float4v*)(xp + 256 + lane * 4);
            r2 = *(const float4v*)(xp + 512 + lane * 4);
            r3 = xp[768 + lane];
        }

        // input-layer B fragments (stride-13 dword gather: conflict-free).
        // B'[n=col][k=8g+j] = x[n][4g+j] for j<4 (garbage past 13 killed by
        // zero A'-columns), j>=4 -> 0.
        half8v bf[T];
#pragma unroll
        for (int t = 0; t < T; ++t) {
            const unsigned* p = xs + t * 208 + col13k;
            bf[t] = frag8(pkh(__uint_as_float(p[0]), __uint_as_float(p[1])),
                          pkh(__uint_as_float(p[2]), __uint_as_float(p[3])));
        }

        // ---- 31 layers, A/bias prefetched one ahead; bias rides in C ----
        uint2 aC = lA[lane];           // layer 0 packed A pair
        float4v cC = lB[g];
#pragma unroll
        for (int L = 0; L < NL - 1; ++L) {
            const uint2 aN = lA[(L + 1) * 64 + lane];
            const float4v cN = lB[(L + 1) * 4 + g];
            const half8v aF = frag8(aC.x, aC.y);
            float4v d[T];
#pragma unroll
            for (int t = 0; t < T; ++t)
                d[t] = __builtin_amdgcn_mfma_f32_16x16x32_f16(aF, bf[t], cC, 0, 0, 0);
#pragma unroll
            for (int t = 0; t < T; ++t)
                bf[t] = relu_frag8(d[t]);
            aC = aN;
            cC = cN;
        }

        // output layer: W_out lives in row 0 only; y[n] = D[0][n]
        {
            const half8v aF = frag8(aC.x, aC.y);
#pragma unroll
            for (int t = 0; t < T; ++t) {
                float4v d = __builtin_amdgcn_mfma_f32_16x16x32_f16(aF, bf[t], cC, 0, 0, 0);
                if (lane < 16) op[t * 16] = d[0];
            }
        }
        op += (size_t)STRIDE * 16;
    }
}

extern "C" void kernel_launch(void* const* d_in, const int* in_sizes, int n_in,
                              void* d_out, int out_size, void* d_ws, size_t ws_size,
                              hipStream_t stream) {
    const float* x     = (const float*)d_in[0];
    const float* W_in  = (const float*)d_in[1];
    const float* b_in  = (const float*)d_in[2];
    const float* W_h   = (const float*)d_in[3];
    const float* b_h   = (const float*)d_in[4];
    const float* W_out = (const float*)d_in[5];
    const float* b_out = (const float*)d_in[6];
    float* out = (float*)d_out;

    const int tiles = out_size / 16;                       // 131072
    int blocks = (tiles + WPB * T - 1) / (WPB * T);
    if (blocks > NBLOCKS) blocks = NBLOCKS;
    mlp_kernel<<<blocks, TPB, 0, stream>>>(x, W_in, b_in, W_h, b_h, W_out, b_out,
                                           out, tiles);
}

// Round 12
// 189.012 us; speedup vs baseline: 1.0816x; 1.0816x over previous
//
#include <hip/hip_runtime.h>
#include <stdint.h>

// Batched tiny MLP [B,13]->16->(30x 16->16 relu)->1, fp32 in/out, f16 MFMA.
// Transposed formulation: mfma_f32_16x16x16_f16 D layout == B layout, so each
// layer's relu'd output is the next layer's B fragment in-register.
// R12: occupancy attack. Shape analysis (R8 vs R11) shows every MFMA shape
// costs ~16.2 cyc/SIMD per useful 16-sample tile-layer -> MFMA floor ~66k
// cyc/SIMD; R8 runs at 38% pipe fill with 6 waves/SIMD. This round: TPB=1024
// (16 waves/block) amortizes the 18KB weight LDS -> 71.7KB/block = 2
// blocks/CU = 8 waves/SIMD; launch_bounds(1024,8) caps VGPR at 64 (R8 used
// 40 -- safe). Also 2-layer-ahead A/bias prefetch to cover ds_read latency.

typedef __attribute__((ext_vector_type(4))) _Float16 half4v;
typedef __attribute__((ext_vector_type(2))) _Float16 h2;
typedef __attribute__((ext_vector_type(4))) float float4v;

#define S_IN 13
#define H 16
#define NL 32            // mfma layers: 0 = input, 1..30 = hidden, 31 = output
#define TPB 1024
#define WPB 16           // waves per block
#define T 4              // 16-sample tiles per wave per iteration
#define NBLOCKS 512      // 2 blocks/CU * 256 CUs (LDS-limited residency)
#define STRIDE (NBLOCKS * WPB * T)   // tiles per grid sweep = 32768

// LDS dword map:
//   [0, 4096)            A-frags: 2 dwords (4 f16) per (L, lane)
//   [4096, 4608)         bias[L][m] fp32 (C-operand order)
//   [4608, 4608+WPB*832) per-wave x staging (4 tiles * 16 samples * 13 dw)
//   +4 zero pad (input-frag gather may overshoot by up to 3 dwords)
#define XS_BASE 4608
#define LDS_DW (XS_BASE + WPB * 832 + 4)

__device__ __forceinline__ unsigned pkh(float a, float b) {
    return __builtin_bit_cast(unsigned, __builtin_amdgcn_cvt_pkrtz(a, b));
}

__device__ __forceinline__ half4v pack4h(float v0, float v1, float v2, float v3) {
    int2 p;
    p.x = (int)pkh(v0, v1);
    p.y = (int)pkh(v2, v3);
    return __builtin_bit_cast(half4v, p);
}

// cvt then packed-f16 relu: 2 cvt + 2 v_pk_max_f16
__device__ __forceinline__ half4v relu_pack4h(const float4v& d) {
    const h2 z = {(_Float16)0.f, (_Float16)0.f};
    h2 lo = __builtin_bit_cast(h2, pkh(d[0], d[1]));
    h2 hi = __builtin_bit_cast(h2, pkh(d[2], d[3]));
    lo = __builtin_elementwise_max(lo, z);
    hi = __builtin_elementwise_max(hi, z);
    int2 p;
    p.x = __builtin_bit_cast(int, lo);
    p.y = __builtin_bit_cast(int, hi);
    return __builtin_bit_cast(half4v, p);
}

__global__ __launch_bounds__(TPB, 8)
void mlp_kernel(const float* __restrict__ x,
                const float* __restrict__ W_in, const float* __restrict__ b_in,
                const float* __restrict__ W_h,  const float* __restrict__ b_h,
                const float* __restrict__ W_out,const float* __restrict__ b_out,
                float* __restrict__ out, int tiles)
{
    __shared__ unsigned lds[LDS_DW];
    const int tid = threadIdx.x;

    // ---- swizzle weights into f16 A-fragment layout in LDS (once/block) ----
    for (int s = tid; s < NL * 64; s += TPB) {
        const int L = s >> 6, ln = s & 63, m = ln & 15, gg = ln >> 4;
        float v[4];
#pragma unroll
        for (int i = 0; i < 4; ++i) {
            const int k = 4 * gg + i;
            if (L == 0)       v[i] = (k < S_IN) ? W_in[m * S_IN + k] : 0.f;
            else if (L <= 30) v[i] = W_h[(L - 1) * H * H + m * H + k];
            else              v[i] = (m == 0) ? W_out[k] : 0.f;
        }
        lds[s * 2]     = pkh(v[0], v[1]);
        lds[s * 2 + 1] = pkh(v[2], v[3]);
    }
    for (int s = tid; s < NL * H; s += TPB) {
        const int L = s >> 4, m = s & 15;
        float bv;
        if (L == 0)       bv = b_in[m];
        else if (L <= 30) bv = b_h[(L - 1) * H + m];
        else              bv = (m == 0) ? b_out[0] : 0.f;
        lds[4096 + s] = __float_as_uint(bv);
    }
    if (tid < 4) lds[XS_BASE + WPB * 832 + tid] = 0;   // zero overshoot pad
    __syncthreads();

    const half4v* lA = (const half4v*)lds;             // [NL*64], 8B elems
    const float4v* lB = (const float4v*)(lds + 4096);  // [NL*4]

    const int lane = tid & 63;
    const int wv   = tid >> 6;
    const int g    = lane >> 4;
    const int col  = lane & 15;
    const int k0   = 4 * g;
    const int col13k = col * 13 + k0;

    unsigned* xs = lds + XS_BASE + wv * 832;           // wave-private staging

    const int wave_id = blockIdx.x * WPB + wv;
    int tb = wave_id * T;
    if (tb >= tiles) return;

    float* op = out + (size_t)tb * 16 + lane;

    // prefetch first iteration's x block (4 tiles = 832 dwords, coalesced)
    const float* xp = x + (size_t)tb * 208;
    float4v r0 = *(const float4v*)(xp + lane * 4);
    float4v r1 = *(const float4v*)(xp + 256 + lane * 4);
    float4v r2 = *(const float4v*)(xp + 512 + lane * 4);
    float    r3 = xp[768 + lane];

    for (; tb < tiles; tb += STRIDE) {
        // stage current x block (wave-private: no barrier needed)
        *(float4v*)(xs + lane * 4)       = r0;
        *(float4v*)(xs + 256 + lane * 4) = r1;
        *(float4v*)(xs + 512 + lane * 4) = r2;
        xs[768 + lane] = __float_as_uint(r3);

        // issue next iteration's global loads (in flight across layer chain)
        const int tbn = tb + STRIDE;
        if (tbn < tiles) {
            xp = x + (size_t)tbn * 208;
            r0 = *(const float4v*)(xp + lane * 4);
            r1 = *(const float4v*)(xp + 256 + lane * 4);
            r2 = *(const float4v*)(xp + 512 + lane * 4);
            r3 = xp[768 + lane];
        }

        // input-layer B fragments (stride-13 dword gather: conflict-free).
        // k slots 13..15 read neighbor x / zero pad: finite, A there is 0.
        half4v bf[T];
#pragma unroll
        for (int t = 0; t < T; ++t) {
            const unsigned* p = xs + t * 208 + col13k;
            bf[t] = pack4h(__uint_as_float(p[0]), __uint_as_float(p[1]),
                           __uint_as_float(p[2]), __uint_as_float(p[3]));
        }

        // ---- 31 layers, A/bias prefetched TWO ahead; bias rides in C ----
        half4v aC = lA[lane];              // layer 0
        half4v aN = lA[64 + lane];         // layer 1
        float4v cC = lB[g];
        float4v cN = lB[4 + g];
#pragma unroll
        for (int L = 0; L < NL - 1; ++L) {
            half4v aN2;
            float4v cN2;
            if (L + 2 < NL) {
                aN2 = lA[(L + 2) * 64 + lane];
                cN2 = lB[(L + 2) * 4 + g];
            }
            float4v d[T];
#pragma unroll
            for (int t = 0; t < T; ++t)
                d[t] = __builtin_amdgcn_mfma_f32_16x16x16f16(aC, bf[t], cC, 0, 0, 0);
#pragma unroll
            for (int t = 0; t < T; ++t)
                bf[t] = relu_pack4h(d[t]);
            aC = aN; aN = aN2;
            cC = cN; cN = cN2;
        }

        // output layer: W_out lives in row 0 only; y[n] = D[0][n]
#pragma unroll
        for (int t = 0; t < T; ++t) {
            float4v d = __builtin_amdgcn_mfma_f32_16x16x16f16(aC, bf[t], cC, 0, 0, 0);
            if (lane < 16) op[t * 16] = d[0];
        }
        op += (size_t)STRIDE * 16;
    }
}

extern "C" void kernel_launch(void* const* d_in, const int* in_sizes, int n_in,
                              void* d_out, int out_size, void* d_ws, size_t ws_size,
                              hipStream_t stream) {
    const float* x     = (const float*)d_in[0];
    const float* W_in  = (const float*)d_in[1];
    const float* b_in  = (const float*)d_in[2];
    const float* W_h   = (const float*)d_in[3];
    const float* b_h   = (const float*)d_in[4];
    const float* W_out = (const float*)d_in[5];
    const float* b_out = (const float*)d_in[6];
    float* out = (float*)d_out;

    const int tiles = out_size / 16;                       // 131072
    int blocks = (tiles + WPB * T - 1) / (WPB * T);
    if (blocks > NBLOCKS) blocks = NBLOCKS;
    mlp_kernel<<<blocks, TPB, 0, stream>>>(x, W_in, b_in, W_h, b_h, W_out, b_out,
                                           out, tiles);
}